// Round 6
// baseline (283.080 us; speedup 1.0000x reference)
//
#include <hip/hip_runtime.h>

// FWHT along axis 1 of (64, 1024, 512) fp32, unnormalized (a+b, a-b), h=1..512.
// Round 7: vectorize K1 to dwordx4. Evidence from R6 counters:
//  - fillBufferAligned (harness reset): 6.7 TB/s  -> device sustains 6.7.
//  - K2 (float4, 64KB-stride):          ~9 TB/s eff (L3) in ~28 us -> fine.
//  - K1 (sequential but SCALAR dword):   2.53 TB/s, 79.5 us        -> slow.
// The limiter in K1 is instruction width, not the address stream: one
// thread = one column forces 4 B/lane (256 B/wave-instr). Guideline 13's
// 2-2.5x scalar penalty applies to strided fp32 layouts too: 2.53 x 2.3 ~ 5.8.
// Fix: thread owns 4 consecutive cols -> float4 u[64] register butterfly,
// every global access is dwordx4 (1 KB/wave-instr, slab-sequential).
// ~270 VGPR (static indices only; no spill through 450 per m08), 256-thread
// blocks = 2 slabs/block, grid 512. ~4 waves/CU is enough: no barriers, and
// 63 outstanding dwordx4/wave >> the ~10 KB/CU BW*latency product.
//
// Factorization (unchanged): H_1024 = H_16(bits 6..9) o H_64(bits 0..5).
// K1: H_64 per 64-consecutive-row slab (contiguous 128 KB), pure registers.
// K2: H_16 over rows {ghi*64 + r} in place; each block owns rows r mod 64
//     == r for all 512 cols -> no inter-block races; same-stream ordering.

constexpr int NB = 64;    // batch
constexpr int NR = 1024;  // transform length (axis 1)
constexpr int ND = 512;   // inner dim

// ---------------- K1: H_64 on 64-row slabs, float4-wide --------------------
// 256 threads = 2 slabs x 128 col-quads; grid = NB*(NR/64)/2 = 512.
__global__ __launch_bounds__(256, 1)
void fwht_k1(const float* __restrict__ x, float* __restrict__ y) {
    const int tid = threadIdx.x;
    const int sid = blockIdx.x * 2 + (tid >> 7);   // slab 0..1023
    const int q   = tid & 127;                     // col-quad 0..127
    const size_t base = (size_t)sid * (64 * ND) + (size_t)(q * 4);

    float4 u[64];
#pragma unroll
    for (int i = 0; i < 64; ++i)
        u[i] = *reinterpret_cast<const float4*>(&x[base + (size_t)i * ND]);

    // H_64 over i (global stages h = 1..32)
#pragma unroll
    for (int hb = 1; hb < 64; hb <<= 1) {
#pragma unroll
        for (int i = 0; i < 64; ++i) {
            if ((i & hb) == 0) {
                const int k = i | hb;
                float4 a = u[i], bb = u[k];
                u[i] = make_float4(a.x + bb.x, a.y + bb.y, a.z + bb.z, a.w + bb.w);
                u[k] = make_float4(a.x - bb.x, a.y - bb.y, a.z - bb.z, a.w - bb.w);
            }
        }
    }

#pragma unroll
    for (int i = 0; i < 64; ++i)
        *reinterpret_cast<float4*>(&y[base + (size_t)i * ND]) = u[i];
}

// ---------------- K2: H_16 over the high 4 bits, in place ------------------
// block = (b, r): rows n = ghi*64 + r, ghi in [0,16). 128 threads, thread
// owns cols 4q..4q+3. grid = NB * 64 = 4096 blocks. (R6: ~28 us, ~9 TB/s
// effective via L3 -- unchanged.)
__global__ __launch_bounds__(128)
void fwht_k2(float* __restrict__ y) {
    const int q   = threadIdx.x;                 // float4 column 0..127
    const int pid = blockIdx.x;                  // b*64 + r
    const int b   = pid >> 6;
    const int r   = pid & 63;
    const size_t base = ((size_t)b * NR + (size_t)r) * ND + (size_t)(q * 4);
    constexpr size_t RSTEP = (size_t)64 * ND;    // 64 rows = 32768 floats

    float4 v[16];
#pragma unroll
    for (int g = 0; g < 16; ++g)
        v[g] = *reinterpret_cast<const float4*>(&y[base + (size_t)g * RSTEP]);

    // H_16 over g (global stages h = 64,128,256,512)
#pragma unroll
    for (int hb = 1; hb < 16; hb <<= 1) {
#pragma unroll
        for (int g = 0; g < 16; ++g) {
            if ((g & hb) == 0) {
                const int k = g | hb;
                float4 a = v[g], bb = v[k];
                v[g] = make_float4(a.x + bb.x, a.y + bb.y, a.z + bb.z, a.w + bb.w);
                v[k] = make_float4(a.x - bb.x, a.y - bb.y, a.z - bb.z, a.w - bb.w);
            }
        }
    }

#pragma unroll
    for (int g = 0; g < 16; ++g)
        *reinterpret_cast<float4*>(&y[base + (size_t)g * RSTEP]) = v[g];
}

extern "C" void kernel_launch(void* const* d_in, const int* in_sizes, int n_in,
                              void* d_out, int out_size, void* d_ws, size_t ws_size,
                              hipStream_t stream) {
    const float* x = (const float*)d_in[0];
    float* y = (float*)d_out;
    fwht_k1<<<dim3(NB * (NR / 64) / 2), dim3(256), 0, stream>>>(x, y);
    fwht_k2<<<dim3(NB * 64), dim3(128), 0, stream>>>(y);
}